// Round 5
// baseline (4362.287 us; speedup 1.0000x reference)
//
#include <hip/hip_runtime.h>

typedef float v4 __attribute__((ext_vector_type(4)));
typedef float v2 __attribute__((ext_vector_type(2)));

#define BLOCK 512
constexpr int RROWS = 64;              // rows per block
constexpr int XC   = 224;
constexpr int HREV = 32;
constexpr int HFWD = 64;
constexpr int U    = 128;
constexpr int NPAIR = 96;              // v-region col pairs (cols 32..223)
// LDS layout (floats)
constexpr int W1_FL   = 97 * U;        // 12416
constexpr int W2_FL   = U * U;         // 16384
constexpr int H1_STR  = U + 4;         // 132 (pad: ≡4 mod 32 banks -> 2-way free)
constexpr int BUF_STR = HREV + 4;      // 36
constexpr int H1_FL   = RROWS * H1_STR;   // 8448
constexpr int BUF_FL  = RROWS * BUF_STR;  // 2304
constexpr int PART_FL = 8 * RROWS;        // 512
constexpr int LDS_FL  = W1_FL + W2_FL + H1_FL + BUF_FL + PART_FL; // 40064 fl = 160256 B

// ---------------- transpose prepass: xp[block][pair p][row] = {x[r][32+2p], x[r][33+2p]} ----------------
extern "C" __global__ __launch_bounds__(256)
void xpose_kernel(const float* __restrict__ x, v2* __restrict__ xp)
{
    __shared__ v2 tile[RROWS][NPAIR + 1];    // 49.9 KB, +1 pad breaks bank aliasing
    const long row0 = (long)blockIdx.x * RROWS;
    for (int idx = threadIdx.x; idx < RROWS * NPAIR; idx += 256) {
        int r = idx / NPAIR, p = idx - r * NPAIR;           // lanes scan p: coalesced read
        tile[r][p] = *(const v2*)(x + (row0 + r) * XC + HREV + 2 * p);
    }
    __syncthreads();
    v2* dst = xp + (size_t)blockIdx.x * NPAIR * RROWS;
    for (int idx = threadIdx.x; idx < RROWS * NPAIR; idx += 256) {
        int p = idx / RROWS, r = idx - p * RROWS;           // lanes scan r: coalesced write
        dst[p * RROWS + r] = tile[r][p];
    }
}

// ---------------- main kernel ----------------
// 8 waves; wave w owns neurons [16w,16w+16). lane: rtl = l&15 (row), ntl = l>>4 (neuron quad).
// thread tile: 4 rows (rtl+16*rr) x 4 neurons.
template<bool XP>
__global__ __launch_bounds__(BLOCK, 2)
void rmlp_kernel(const float* __restrict__ x, const v2* __restrict__ xp,
                 const float* __restrict__ W1, const float* __restrict__ b1,
                 const float* __restrict__ W2, const float* __restrict__ b2,
                 const float* __restrict__ W3, const float* __restrict__ b3,
                 float* __restrict__ out)
{
    extern __shared__ float lds[];
    float* W1s   = lds;                  // [97][128]
    float* W2s   = W1s + W1_FL;          // [128][128]
    float* h1s   = W2s + W2_FL;          // [64][132]
    float* bufs  = h1s + H1_FL;          // [64][36]
    float* parts = bufs + BUF_FL;        // [8][64]

    const int t   = threadIdx.x;
    const int wv  = t >> 6;              // wave 0..7
    const int l   = t & 63;
    const int rtl = l & 15;
    const int ntl = l >> 4;              // 0..3
    const int wq  = wv * 4 + ntl;        // v4 column index of this thread's 4 neurons
    const int n0  = wq * 4;
    const long row0 = (long)blockIdx.x * RROWS;

    // stage weights (linear, coalesced)
    {
        const v4* g1 = (const v4*)W1; v4* s1 = (v4*)W1s;
        for (int idx = t; idx < W1_FL / 4; idx += BLOCK) s1[idx] = g1[idx];
        const v4* g2 = (const v4*)W2; v4* s2 = (v4*)W2s;
        for (int idx = t; idx < W2_FL / 4; idx += BLOCK) s2[idx] = g2[idx];
    }
    // buf init: e = x[:, :32] into padded rows
    {
        int br = t >> 3, bc = t & 7;
        v4 e = *(const v4*)(x + (row0 + br) * XC + bc * 4);
        *(v4*)(bufs + br * BUF_STR + bc * 4) = e;
    }
    float b1v[4], b2v[4], w3v[4], w196[4];
    #pragma unroll
    for (int j = 0; j < 4; ++j) {
        b1v[j]  = b1[n0 + j];
        b2v[j]  = b2[n0 + j];
        w3v[j]  = W3[n0 + j];
        w196[j] = W1[96 * U + n0 + j];
    }
    const float b3s = b3[0];

    int roff[4];
    const float* xr[4];
    #pragma unroll
    for (int rr = 0; rr < 4; ++rr) {
        roff[rr] = rtl + 16 * rr;
        xr[rr]   = x + (row0 + roff[rr]) * XC + HREV;
    }
    const v2* xpb = XP ? (xp + (size_t)blockIdx.x * NPAIR * RROWS) : nullptr;

    const int srow = t >> 3;            // shift duty
    const int sc   = (t & 7) * 4;

    __syncthreads();

    const v4* W1s4 = (const v4*)W1s;
    const v4* W2s4 = (const v4*)W2s;

    for (int i = 0; i < HFWD; ++i) {
        const float fi = (float)i;
        // ---------- layer 1 ----------
        float a1[4][4];
        #pragma unroll
        for (int rr = 0; rr < 4; ++rr)
            #pragma unroll
            for (int j = 0; j < 4; ++j)
                a1[rr][j] = fmaf(fi, w196[j], b1v[j]);

        // k=0..31: buf part
        #pragma unroll 2
        for (int kc = 0; kc < 8; ++kc) {
            v4 w[4];
            #pragma unroll
            for (int kk = 0; kk < 4; ++kk) w[kk] = W1s4[(kc * 4 + kk) * 32 + wq];
            #pragma unroll
            for (int rr = 0; rr < 4; ++rr) {
                v4 d = *(const v4*)(bufs + roff[rr] * BUF_STR + kc * 4);
                #pragma unroll
                for (int kk = 0; kk < 4; ++kk)
                    #pragma unroll
                    for (int j = 0; j < 4; ++j)
                        a1[rr][j] = fmaf(d[kk], w[kk][j], a1[rr][j]);
            }
        }
        // k=32..95: v part
        const v2* xpi = XP ? (xpb + i * RROWS) : nullptr;
        #pragma unroll 2
        for (int qc = 0; qc < 16; ++qc) {
            v4 w[4];
            #pragma unroll
            for (int kk = 0; kk < 4; ++kk) w[kk] = W1s4[(HREV + qc * 4 + kk) * 32 + wq];
            #pragma unroll
            for (int rr = 0; rr < 4; ++rr) {
                v2 lo, hi;
                if (XP) {
                    lo = xpi[(2 * qc) * RROWS + roff[rr]];
                    hi = xpi[(2 * qc + 1) * RROWS + roff[rr]];
                } else {
                    const float* p = xr[rr] + 2 * i + qc * 4;
                    lo = *(const v2*)p; hi = *(const v2*)(p + 2);
                }
                #pragma unroll
                for (int j = 0; j < 4; ++j) {
                    a1[rr][j] = fmaf(lo[0], w[0][j], a1[rr][j]);
                    a1[rr][j] = fmaf(lo[1], w[1][j], a1[rr][j]);
                    a1[rr][j] = fmaf(hi[0], w[2][j], a1[rr][j]);
                    a1[rr][j] = fmaf(hi[1], w[3][j], a1[rr][j]);
                }
            }
        }
        // write h1 = relu(a1)
        #pragma unroll
        for (int rr = 0; rr < 4; ++rr) {
            v4 h;
            #pragma unroll
            for (int j = 0; j < 4; ++j) h[j] = fmaxf(a1[rr][j], 0.0f);
            *(v4*)(h1s + roff[rr] * H1_STR + wq * 4) = h;
        }
        // buf shift reads (pad col 32 exists, value unused)
        float sv0 = bufs[srow * BUF_STR + sc + 1];
        float sv1 = bufs[srow * BUF_STR + sc + 2];
        float sv2 = bufs[srow * BUF_STR + sc + 3];
        float sv3 = bufs[srow * BUF_STR + sc + 4];

        __syncthreads();   // barrier 1: h1 ready, buf reads done

        // ---------- layer 2 ----------
        float a2[4][4];
        #pragma unroll
        for (int rr = 0; rr < 4; ++rr)
            #pragma unroll
            for (int j = 0; j < 4; ++j)
                a2[rr][j] = b2v[j];
        #pragma unroll 4
        for (int jc = 0; jc < 32; ++jc) {
            v4 w[4];
            #pragma unroll
            for (int kk = 0; kk < 4; ++kk) w[kk] = W2s4[(jc * 4 + kk) * 32 + wq];
            #pragma unroll
            for (int rr = 0; rr < 4; ++rr) {
                v4 h = *(const v4*)(h1s + roff[rr] * H1_STR + jc * 4);
                #pragma unroll
                for (int kk = 0; kk < 4; ++kk)
                    #pragma unroll
                    for (int j = 0; j < 4; ++j)
                        a2[rr][j] = fmaf(h[kk], w[kk][j], a2[rr][j]);
            }
        }
        // ---------- layer 3: partial over this wave's 16 neurons ----------
        float pr[4];
        #pragma unroll
        for (int rr = 0; rr < 4; ++rr) {
            float p = 0.0f;
            #pragma unroll
            for (int j = 0; j < 4; ++j)
                p = fmaf(fmaxf(a2[rr][j], 0.0f), w3v[j], p);
            p += __shfl_xor(p, 16, 64);
            p += __shfl_xor(p, 32, 64);
            pr[rr] = p;
        }
        if (ntl == 0) {
            #pragma unroll
            for (int rr = 0; rr < 4; ++rr)
                parts[wv * RROWS + roff[rr]] = pr[rr];
        }
        __syncthreads();   // barrier 2: partials ready

        // ---------- final reduce (wave 0) + buf shift writes (all) ----------
        if (t < 64) {
            float s = b3s;
            #pragma unroll
            for (int w8 = 0; w8 < 8; ++w8) s += parts[w8 * RROWS + t];
            out[(row0 + t) * HFWD + i] = s;
            bufs[t * BUF_STR + 31] = s;
        }
        bufs[srow * BUF_STR + sc + 0] = sv0;
        bufs[srow * BUF_STR + sc + 1] = sv1;
        bufs[srow * BUF_STR + sc + 2] = sv2;
        if (sc + 3 < 31) bufs[srow * BUF_STR + sc + 3] = sv3;

        __syncthreads();   // barrier 3: buf consistent for next step
    }
}

extern "C" void kernel_launch(void* const* d_in, const int* in_sizes, int n_in,
                              void* d_out, int out_size, void* d_ws, size_t ws_size,
                              hipStream_t stream) {
    const float* x  = (const float*)d_in[0];
    const float* W1 = (const float*)d_in[1];
    const float* b1 = (const float*)d_in[2];
    const float* W2 = (const float*)d_in[3];
    const float* b2 = (const float*)d_in[4];
    const float* W3 = (const float*)d_in[5];
    const float* b3 = (const float*)d_in[6];
    float* out = (float*)d_out;

    const int B    = in_sizes[0] / XC;      // 65536
    const int nblk = B / RROWS;             // 1024
    const size_t xp_bytes = (size_t)nblk * NPAIR * RROWS * sizeof(v2); // ~50.3 MB

    if (ws_size >= xp_bytes) {
        v2* xp = (v2*)d_ws;
        hipFuncSetAttribute((const void*)rmlp_kernel<true>,
                            hipFuncAttributeMaxDynamicSharedMemorySize, LDS_FL * 4);
        xpose_kernel<<<nblk, 256, 0, stream>>>(x, xp);
        rmlp_kernel<true><<<nblk, BLOCK, LDS_FL * 4, stream>>>(x, xp, W1, b1, W2, b2, W3, b3, out);
    } else {
        hipFuncSetAttribute((const void*)rmlp_kernel<false>,
                            hipFuncAttributeMaxDynamicSharedMemorySize, LDS_FL * 4);
        rmlp_kernel<false><<<nblk, BLOCK, LDS_FL * 4, stream>>>(x, nullptr, W1, b1, W2, b2, W3, b3, out);
    }
}

// Round 8
// 981.158 us; speedup vs baseline: 4.4461x; 4.4461x over previous
//
#include <hip/hip_runtime.h>

typedef float  v2f  __attribute__((ext_vector_type(2)));
typedef float  v4f  __attribute__((ext_vector_type(4)));
typedef float  f32x4 __attribute__((ext_vector_type(4)));
typedef __bf16 bf16x8 __attribute__((ext_vector_type(8)));
typedef __bf16 bf16x4 __attribute__((ext_vector_type(4)));

constexpr int XC    = 224;
constexpr int HREV  = 32;
constexpr int HFWD  = 64;
constexpr int U     = 128;
constexpr int RROWS = 64;
#define BLOCK 512

// LDS layout in bf16 halfword units (all planes swizzled: halfidx ^= (rowsel)<<3 == byte^16B)
constexpr int W1T_PL  = 128 * 96;            // per plane
constexpr int W2T_PL  = 128 * 128;
constexpr int H1_PL   = 64 * 128;
constexpr int BUF_PL  = 64 * 32;
constexpr int W1T_OFF = 0;
constexpr int W2T_OFF = W1T_OFF + 2 * W1T_PL;   // 24576
constexpr int H1_OFF  = W2T_OFF + 2 * W2T_PL;   // 57344
constexpr int BUF_OFF = H1_OFF  + 2 * H1_PL;    // 73728
constexpr int PART_OFF= BUF_OFF + 2 * BUF_PL;   // 77824 halfwords = 155648 B
constexpr int LDS_BYTES = PART_OFF * 2 + 2 * 64 * 4;  // +512B partials = 156160 B

static __device__ __forceinline__ f32x4 mfma16(bf16x8 a, bf16x8 b, f32x4 c) {
    return __builtin_amdgcn_mfma_f32_16x16x32_bf16(a, b, c, 0, 0, 0);
}
static __device__ __forceinline__ void split(float v, __bf16& h, __bf16& l) {
    h = (__bf16)v; l = (__bf16)(v - (float)h);
}

// 8 waves. wave w: row-tile rt=w&3 (batch rows 16rt..16rt+15), n-group g=w>>2 (neurons 64g..64g+63).
// lane l: lr=l&15 (batch row within tile / A-row), lg=l>>4 (k-group).
// MFMA 16x16x32 bf16, swapped operands: A = W^T fragment (M=neuron), B = data^T fragment (N=batch row).
// C/D: col=l&15 (batch row), row=(l>>4)*4+reg (neuron)  [m89-verified layout].
extern "C" __global__ __launch_bounds__(BLOCK)
void rmlp_mfma(const float* __restrict__ x,  const float* __restrict__ W1,
               const float* __restrict__ b1, const float* __restrict__ W2,
               const float* __restrict__ b2, const float* __restrict__ W3,
               const float* __restrict__ b3, float* __restrict__ out)
{
    extern __shared__ __align__(16) char smem[];
    __bf16* hw   = (__bf16*)smem;
    __bf16* W1Th = hw + W1T_OFF;  __bf16* W1Tl = W1Th + W1T_PL;   // [n=128][k=96]
    __bf16* W2Th = hw + W2T_OFF;  __bf16* W2Tl = W2Th + W2T_PL;   // [n2=128][n1=128]
    __bf16* h1h  = hw + H1_OFF;   __bf16* h1l  = h1h + H1_PL;     // [row=64][n=128]
    __bf16* bufh = hw + BUF_OFF;  __bf16* bufl = bufh + BUF_PL;   // [row=64][k=32]
    float*  parts = (float*)(hw + PART_OFF);                      // [2][64]

    const int t  = threadIdx.x;
    const int w  = t >> 6, l = t & 63;
    const int rt = w & 3,  g = w >> 2;
    const int lr = l & 15, lg = l >> 4;
    const long row0 = (long)blockIdx.x * RROWS;

    // ---- stage W1^T split+swizzled (rows 0..95; row 96 folded into bias) ----
    for (int idx = t; idx < 96 * 128; idx += BLOCK) {
        int k = idx >> 7, n = idx & 127;                 // coalesced read over n
        float v = W1[k * U + n];
        __bf16 h, lo; split(v, h, lo);
        int o = (n * 96 + k) ^ ((n & 7) << 3);
        W1Th[o] = h; W1Tl[o] = lo;
    }
    // ---- stage W2^T split+swizzled ----
    for (int idx = t; idx < 128 * 128; idx += BLOCK) {
        int n1 = idx >> 7, n2 = idx & 127;
        float v = W2[n1 * U + n2];
        __bf16 h, lo; split(v, h, lo);
        int o = (n2 * 128 + n1) ^ ((n2 & 7) << 3);
        W2Th[o] = h; W2Tl[o] = lo;
    }
    // ---- buf init: e = x[:, :32], split into planes ----
    {
        int r = t >> 3, c0 = (t & 7) * 4;
        v4f e = *(const v4f*)(x + (row0 + r) * XC + c0);
        #pragma unroll
        for (int j = 0; j < 4; ++j) {
            __bf16 h, lo; split(e[j], h, lo);
            int o = (r * 32 + c0 + j) ^ ((r & 3) << 3);
            bufh[o] = h; bufl[o] = lo;
        }
    }
    // ---- per-lane hoists: n(t_,q) = g*64 + t_*16 + lg*4 + q (matches C-frag rows) ----
    float b1v[4][4], w196[4][4], b2v[4][4], w3v[4][4];
    #pragma unroll
    for (int t_ = 0; t_ < 4; ++t_)
        #pragma unroll
        for (int q = 0; q < 4; ++q) {
            int n = g * 64 + t_ * 16 + lg * 4 + q;
            b1v[t_][q]  = b1[n];
            w196[t_][q] = W1[96 * U + n];
            b2v[t_][q]  = b2[n];
            w3v[t_][q]  = W3[n];
        }
    const float b3s = b3[0];
    const int   br  = rt * 16 + lr;                 // this lane's batch row (block-local)
    const float* xrow = x + (row0 + br) * XC;       // global row base

    // i-invariant fragment half-indices
    const int bufidx = (br * 32 + lg * 8) ^ ((br & 3) << 3);
    const int h1ridx0 = br * 128;                   // + ks*32 + lg*8, swz by br
    const int h1swz  = (br & 7) << 3;

    const int sr = t >> 3, sc = (t & 7) * 4;        // buf shift duty

    __syncthreads();

    for (int i = 0; i < HFWD; ++i) {
        const float fi = (float)i;
        // ================= layer 1 : K=96 (buf 32 | v 64) =================
        f32x4 acc[4];
        #pragma unroll
        for (int t_ = 0; t_ < 4; ++t_)
            #pragma unroll
            for (int q = 0; q < 4; ++q)
                acc[t_][q] = fmaf(fi, w196[t_][q], b1v[t_][q]);   // bias + i*W1[96]

        // kstep 0: buf from LDS planes
        {
            bf16x8 Bh = *(const bf16x8*)(bufh + bufidx);
            bf16x8 Bl = *(const bf16x8*)(bufl + bufidx);
            #pragma unroll
            for (int t_ = 0; t_ < 4; ++t_) {
                int n = g * 64 + t_ * 16 + lr;
                int a = (n * 96 + lg * 8) ^ ((n & 7) << 3);
                bf16x8 Ah = *(const bf16x8*)(W1Th + a);
                bf16x8 Al = *(const bf16x8*)(W1Tl + a);
                acc[t_] = mfma16(Al, Bh, acc[t_]);
                acc[t_] = mfma16(Ah, Bl, acc[t_]);
                acc[t_] = mfma16(Ah, Bh, acc[t_]);
            }
        }
        // ksteps 1,2: v from global (f32, split in-register). x col = 32 + 2i + vk
        #pragma unroll
        for (int ks = 1; ks <= 2; ++ks) {
            const float* p = xrow + 32 + 2 * i + (ks - 1) * 32 + lg * 8;  // 8B-aligned
            v2f d0 = *(const v2f*)(p);
            v2f d1 = *(const v2f*)(p + 2);
            v2f d2 = *(const v2f*)(p + 4);
            v2f d3 = *(const v2f*)(p + 6);
            float f[8] = {d0[0], d0[1], d1[0], d1[1], d2[0], d2[1], d3[0], d3[1]};
            bf16x8 Bh, Bl;
            #pragma unroll
            for (int j = 0; j < 8; ++j) { __bf16 h, lo; split(f[j], h, lo); Bh[j] = h; Bl[j] = lo; }
            #pragma unroll
            for (int t_ = 0; t_ < 4; ++t_) {
                int n = g * 64 + t_ * 16 + lr;
                int a = (n * 96 + ks * 32 + lg * 8) ^ ((n & 7) << 3);
                bf16x8 Ah = *(const bf16x8*)(W1Th + a);
                bf16x8 Al = *(const bf16x8*)(W1Tl + a);
                acc[t_] = mfma16(Al, Bh, acc[t_]);
                acc[t_] = mfma16(Ah, Bl, acc[t_]);
                acc[t_] = mfma16(Ah, Bh, acc[t_]);
            }
        }
        // epilogue: relu + split + store h1 (lane holds 4 consecutive n for row br)
        #pragma unroll
        for (int t_ = 0; t_ < 4; ++t_) {
            int nb = g * 64 + t_ * 16 + lg * 4;
            bf16x4 hh, ll;
            #pragma unroll
            for (int q = 0; q < 4; ++q) {
                float v = fmaxf(acc[t_][q], 0.0f);
                __bf16 h, lo; split(v, h, lo);
                hh[q] = h; ll[q] = lo;
            }
            int o = (br * 128 + nb) ^ h1swz;
            *(bf16x4*)(h1h + o) = hh;
            *(bf16x4*)(h1l + o) = ll;
        }
        // buf shift pre-reads (stable until writes after barrier-2)
        __bf16 svh[4], svl[4];
        #pragma unroll
        for (int j = 0; j < 4; ++j) {
            int c = sc + 1 + j;
            if (c < 32) {
                int o = (sr * 32 + c) ^ ((sr & 3) << 3);
                svh[j] = bufh[o]; svl[j] = bufl[o];
            }
        }
        __syncthreads();   // barrier 1: h1 complete

        // ================= layer 2 : K=128 =================
        f32x4 acc2[4];
        #pragma unroll
        for (int t_ = 0; t_ < 4; ++t_)
            #pragma unroll
            for (int q = 0; q < 4; ++q)
                acc2[t_][q] = b2v[t_][q];
        #pragma unroll
        for (int ks = 0; ks < 4; ++ks) {
            int o = (h1ridx0 + ks * 32 + lg * 8) ^ h1swz;
            bf16x8 Bh = *(const bf16x8*)(h1h + o);
            bf16x8 Bl = *(const bf16x8*)(h1l + o);
            #pragma unroll
            for (int t_ = 0; t_ < 4; ++t_) {
                int n2 = g * 64 + t_ * 16 + lr;
                int a = (n2 * 128 + ks * 32 + lg * 8) ^ ((n2 & 7) << 3);
                bf16x8 Ah = *(const bf16x8*)(W2Th + a);
                bf16x8 Al = *(const bf16x8*)(W2Tl + a);
                acc2[t_] = mfma16(Al, Bh, acc2[t_]);
                acc2[t_] = mfma16(Ah, Bl, acc2[t_]);
                acc2[t_] = mfma16(Ah, Bh, acc2[t_]);
            }
        }
        // ================= layer 3 : relu(h2) . W3, lane-local then reduce =================
        float p = 0.0f;
        #pragma unroll
        for (int t_ = 0; t_ < 4; ++t_)
            #pragma unroll
            for (int q = 0; q < 4; ++q)
                p = fmaf(fmaxf(acc2[t_][q], 0.0f), w3v[t_][q], p);
        p += __shfl_xor(p, 16, 64);
        p += __shfl_xor(p, 32, 64);          // sum over this wave's 64 neurons for row br
        if (l < 16) parts[g * 64 + rt * 16 + l] = p;
        __syncthreads();   // barrier 2: partials ready, buf shift-reads done

        // final reduce + output + buf append (rows = threads 0..63)
        if (t < 64) {
            float s = parts[t] + parts[64 + t] + b3s;
            out[(row0 + t) * HFWD + i] = s;
            __bf16 h, lo; split(s, h, lo);
            int o31 = (t * 32 + 31) ^ ((t & 3) << 3);
            bufh[o31] = h; bufl[o31] = lo;
        }
        // buf shift writes (cols 0..30)
        #pragma unroll
        for (int j = 0; j < 4; ++j) {
            int c = sc + j;
            if (c < 31) {
                int o = (sr * 32 + c) ^ ((sr & 3) << 3);
                bufh[o] = svh[j]; bufl[o] = svl[j];
            }
        }
        __syncthreads();   // barrier 3: buf consistent for next step
    }
}

extern "C" void kernel_launch(void* const* d_in, const int* in_sizes, int n_in,
                              void* d_out, int out_size, void* d_ws, size_t ws_size,
                              hipStream_t stream) {
    const float* x  = (const float*)d_in[0];
    const float* W1 = (const float*)d_in[1];
    const float* b1 = (const float*)d_in[2];
    const float* W2 = (const float*)d_in[3];
    const float* b2 = (const float*)d_in[4];
    const float* W3 = (const float*)d_in[5];
    const float* b3 = (const float*)d_in[6];
    float* out = (float*)d_out;

    const int B    = in_sizes[0] / XC;     // 65536
    const int nblk = B / RROWS;            // 1024

    hipFuncSetAttribute((const void*)rmlp_mfma,
                        hipFuncAttributeMaxDynamicSharedMemorySize, LDS_BYTES);
    rmlp_mfma<<<nblk, BLOCK, LDS_BYTES, stream>>>(x, W1, b1, W2, b2, W3, b3, out);
}

// Round 9
// 980.996 us; speedup vs baseline: 4.4468x; 1.0002x over previous
//
#include <hip/hip_runtime.h>

typedef float  v2f    __attribute__((ext_vector_type(2)));
typedef float  f32x4  __attribute__((ext_vector_type(4)));
typedef __bf16 bf16x8 __attribute__((ext_vector_type(8)));
typedef __bf16 bf16x4 __attribute__((ext_vector_type(4)));

constexpr int XC = 224, HFWD = 64, U = 128, RR = 16;   // 16 rows per block
#define BLOCK 256

constexpr int H1_PL  = RR * 128;   // halfwords per h1 plane
constexpr int BUF_PL = RR * 32;

static __device__ __forceinline__ f32x4 mfma16(bf16x8 a, bf16x8 b, f32x4 c) {
    return __builtin_amdgcn_mfma_f32_16x16x32_bf16(a, b, c, 0, 0, 0);
}
static __device__ __forceinline__ void split(float v, __bf16& h, __bf16& l) {
    h = (__bf16)v; l = (__bf16)(v - (float)h);
}

// 4 waves/block; wave g owns neurons [32g, 32g+32) for ALL 16 rows of the block.
// lane l: lr=l&15 (batch row / B-col), lg=l>>4 (k-group). MFMA 16x16x32 bf16,
// A = W^T (M=neuron, register-resident), B = data^T. C/D: col=l&15 (row),
// row=(l>>4)*4+reg (neuron) [m89-verified].
extern "C" __global__ __launch_bounds__(BLOCK, 2)
void rmlp_v4(const float* __restrict__ x,  const float* __restrict__ W1,
             const float* __restrict__ b1, const float* __restrict__ W2,
             const float* __restrict__ b2, const float* __restrict__ W3,
             const float* __restrict__ b3, float* __restrict__ out)
{
    __shared__ __bf16 h1h[H1_PL], h1l[H1_PL], bufh[BUF_PL], bufl[BUF_PL];
    __shared__ float  parts[64];

    const int t  = threadIdx.x;
    const int g  = t >> 6, l = t & 63;
    const int lr = l & 15, lg = l >> 4;
    const long row0 = (long)blockIdx.x * RR;

    // ---- A-fragments (weights, split bf16) -> registers, once ----
    bf16x8 a1h[2][3], a1l[2][3], a2h[2][4], a2l[2][4];
    #pragma unroll
    for (int t_ = 0; t_ < 2; ++t_) {
        const int n = g * 32 + t_ * 16 + lr;
        #pragma unroll
        for (int ks = 0; ks < 3; ++ks)
            #pragma unroll
            for (int j = 0; j < 8; ++j) {
                float v = W1[(ks * 32 + lg * 8 + j) * U + n];
                __bf16 h, lo; split(v, h, lo);
                a1h[t_][ks][j] = h; a1l[t_][ks][j] = lo;
            }
        #pragma unroll
        for (int ks = 0; ks < 4; ++ks)
            #pragma unroll
            for (int j = 0; j < 8; ++j) {
                float v = W2[(ks * 32 + lg * 8 + j) * U + n];
                __bf16 h, lo; split(v, h, lo);
                a2h[t_][ks][j] = h; a2l[t_][ks][j] = lo;
            }
    }
    // ---- per-lane scalars: n(t_,q) = 32g + 16t_ + 4lg + q matches C-frag rows ----
    float b1v[2][4], w196[2][4], b2v[2][4], w3v[2][4];
    #pragma unroll
    for (int t_ = 0; t_ < 2; ++t_)
        #pragma unroll
        for (int q = 0; q < 4; ++q) {
            int n = g * 32 + t_ * 16 + lg * 4 + q;
            b1v[t_][q]  = b1[n];
            w196[t_][q] = W1[96 * U + n];
            b2v[t_][q]  = b2[n];
            w3v[t_][q]  = W3[n];
        }
    const float b3s = b3[0];

    // ---- buf init: e = x[:, :32] split into planes ----
    {
        int r = t >> 4, c0 = (t & 15) * 2;
        v2f e = *(const v2f*)(x + (row0 + r) * XC + c0);
        #pragma unroll
        for (int j = 0; j < 2; ++j) {
            __bf16 h, lo; split(e[j], h, lo);
            int o = (r * 32 + c0 + j) ^ ((r & 3) << 3);
            bufh[o] = h; bufl[o] = lo;
        }
    }
    const float* xrow = x + (row0 + lr) * XC;                 // this lane's batch row
    const int bufidx = (lr * 32 + lg * 8) ^ ((lr & 3) << 3);  // i-invariant
    const int h1swz  = (lr & 7) << 3;
    const int srow   = t >> 4, sc0 = (t & 15) * 2;            // buf shift duty

    __syncthreads();

    for (int i = 0; i < HFWD; ++i) {
        const float fi = (float)i;
        // ================= layer 1 : K=96 (buf | v | v) =================
        f32x4 acc[2];
        #pragma unroll
        for (int t_ = 0; t_ < 2; ++t_)
            #pragma unroll
            for (int q = 0; q < 4; ++q)
                acc[t_][q] = fmaf(fi, w196[t_][q], b1v[t_][q]);

        // hoist v global loads (L1-hot) so latency hides under kstep0 MFMAs
        v2f vv[2][4];
        #pragma unroll
        for (int ks = 0; ks < 2; ++ks) {
            const float* p = xrow + 32 + 2 * i + ks * 32 + lg * 8;   // 8B-aligned
            #pragma unroll
            for (int q = 0; q < 4; ++q) vv[ks][q] = *(const v2f*)(p + 2 * q);
        }
        // kstep 0: buf from LDS planes
        {
            bf16x8 Bh = *(const bf16x8*)(bufh + bufidx);
            bf16x8 Bl = *(const bf16x8*)(bufl + bufidx);
            #pragma unroll
            for (int t_ = 0; t_ < 2; ++t_) {
                acc[t_] = mfma16(a1l[t_][0], Bh, acc[t_]);
                acc[t_] = mfma16(a1h[t_][0], Bl, acc[t_]);
                acc[t_] = mfma16(a1h[t_][0], Bh, acc[t_]);
            }
        }
        // ksteps 1,2: v (split in-register)
        #pragma unroll
        for (int ks = 1; ks <= 2; ++ks) {
            bf16x8 Bh, Bl;
            #pragma unroll
            for (int q = 0; q < 4; ++q) {
                __bf16 h, lo;
                split(vv[ks - 1][q][0], h, lo); Bh[2 * q]     = h; Bl[2 * q]     = lo;
                split(vv[ks - 1][q][1], h, lo); Bh[2 * q + 1] = h; Bl[2 * q + 1] = lo;
            }
            #pragma unroll
            for (int t_ = 0; t_ < 2; ++t_) {
                acc[t_] = mfma16(a1l[t_][ks], Bh, acc[t_]);
                acc[t_] = mfma16(a1h[t_][ks], Bl, acc[t_]);
                acc[t_] = mfma16(a1h[t_][ks], Bh, acc[t_]);
            }
        }
        // epilogue: relu + split + store h1 (4 consecutive n per lane per t_)
        #pragma unroll
        for (int t_ = 0; t_ < 2; ++t_) {
            bf16x4 hh, ll;
            #pragma unroll
            for (int q = 0; q < 4; ++q) {
                float v = fmaxf(acc[t_][q], 0.0f);
                __bf16 h, lo; split(v, h, lo);
                hh[q] = h; ll[q] = lo;
            }
            int o = (lr * 128 + g * 32 + t_ * 16 + lg * 4) ^ h1swz;
            *(bf16x4*)(h1h + o) = hh;
            *(bf16x4*)(h1l + o) = ll;
        }
        // buf shift pre-reads (no writer until after barrier 2)
        __bf16 s0h, s0l, s1h = __bf16(0.f), s1l = __bf16(0.f);
        {
            int o1 = (srow * 32 + sc0 + 1) ^ ((srow & 3) << 3);
            s0h = bufh[o1]; s0l = bufl[o1];
            if (sc0 + 2 < 32) {
                int o2 = (srow * 32 + sc0 + 2) ^ ((srow & 3) << 3);
                s1h = bufh[o2]; s1l = bufl[o2];
            }
        }
        __syncthreads();   // barrier 1: h1 complete

        // ================= layer 2 : K=128 =================
        f32x4 acc2[2];
        #pragma unroll
        for (int t_ = 0; t_ < 2; ++t_)
            #pragma unroll
            for (int q = 0; q < 4; ++q)
                acc2[t_][q] = b2v[t_][q];
        #pragma unroll
        for (int ks = 0; ks < 4; ++ks) {
            int o = (lr * 128 + ks * 32 + lg * 8) ^ h1swz;
            bf16x8 Bh = *(const bf16x8*)(h1h + o);
            bf16x8 Bl = *(const bf16x8*)(h1l + o);
            #pragma unroll
            for (int t_ = 0; t_ < 2; ++t_) {
                acc2[t_] = mfma16(a2l[t_][ks], Bh, acc2[t_]);
                acc2[t_] = mfma16(a2h[t_][ks], Bl, acc2[t_]);
                acc2[t_] = mfma16(a2h[t_][ks], Bh, acc2[t_]);
            }
        }
        // ================= layer 3 ================= 
        float p = 0.0f;
        #pragma unroll
        for (int t_ = 0; t_ < 2; ++t_)
            #pragma unroll
            for (int q = 0; q < 4; ++q)
                p = fmaf(fmaxf(acc2[t_][q], 0.0f), w3v[t_][q], p);
        p += __shfl_xor(p, 16, 64);
        p += __shfl_xor(p, 32, 64);            // sum over wave's 32 neurons, per row lr
        if (l < 16) parts[g * 16 + lr] = p;
        __syncthreads();   // barrier 2: partials ready, buf pre-reads done

        // final reduce + out + buf append (threads 0..15) ; shift writes (all)
        if (t < 16) {
            float s = parts[t] + parts[16 + t] + parts[32 + t] + parts[48 + t] + b3s;
            out[(row0 + t) * HFWD + i] = s;
            __bf16 h, lo; split(s, h, lo);
            int o31 = (t * 32 + 31) ^ ((t & 3) << 3);
            bufh[o31] = h; bufl[o31] = lo;
        }
        {
            int o0 = (srow * 32 + sc0) ^ ((srow & 3) << 3);
            bufh[o0] = s0h; bufl[o0] = s0l;
            if (sc0 + 1 < 31) {
                int o1 = (srow * 32 + sc0 + 1) ^ ((srow & 3) << 3);
                bufh[o1] = s1h; bufl[o1] = s1l;
            }
        }
        __syncthreads();   // barrier 3: buf consistent for next step
    }
}

extern "C" void kernel_launch(void* const* d_in, const int* in_sizes, int n_in,
                              void* d_out, int out_size, void* d_ws, size_t ws_size,
                              hipStream_t stream) {
    const float* x  = (const float*)d_in[0];
    const float* W1 = (const float*)d_in[1];
    const float* b1 = (const float*)d_in[2];
    const float* W2 = (const float*)d_in[3];
    const float* b2 = (const float*)d_in[4];
    const float* W3 = (const float*)d_in[5];
    const float* b3 = (const float*)d_in[6];
    float* out = (float*)d_out;

    const int B    = in_sizes[0] / XC;   // 65536
    const int nblk = B / RR;             // 4096

    rmlp_v4<<<nblk, BLOCK, 0, stream>>>(x, W1, b1, W2, b2, W3, b3, out);
}

// Round 10
// 934.887 us; speedup vs baseline: 4.6661x; 1.0493x over previous
//
#include <hip/hip_runtime.h>

typedef float  v2f    __attribute__((ext_vector_type(2)));
typedef float  f32x4  __attribute__((ext_vector_type(4)));
typedef __bf16 bf16x8 __attribute__((ext_vector_type(8)));
typedef __bf16 bf16x4 __attribute__((ext_vector_type(4)));

constexpr int XC = 224, HFWD = 64, U = 128, RR = 16;   // 16 rows per block
#define BLOCK 256

constexpr int H1_PL = RR * 128;   // halfwords per h1 plane

static __device__ __forceinline__ f32x4 mfma16(bf16x8 a, bf16x8 b, f32x4 c) {
    return __builtin_amdgcn_mfma_f32_16x16x32_bf16(a, b, c, 0, 0, 0);
}
static __device__ __forceinline__ void split(float v, __bf16& h, __bf16& l) {
    h = (__bf16)v; l = (__bf16)(v - (float)h);
}
static __device__ __forceinline__ unsigned short bfb(__bf16 b) {
    return __builtin_bit_cast(unsigned short, b);
}
static __device__ __forceinline__ __bf16 bbf(unsigned short u) {
    return __builtin_bit_cast(__bf16, u);
}

// 4 waves/block; wave g owns neurons [32g,32g+32) for all 16 rows. lane: lr=l&15
// (batch row / B-col), lg=l>>4 (k-group). A = W^T register-resident; buf (recurrent
// window) register-resident per lane: B[k=lg*8+j][row=lr], identical copy per wave.
// C/D: col=l&15 (row), row=(l>>4)*4+reg (neuron) [m89-verified].
extern "C" __global__ __launch_bounds__(BLOCK, 2)
void rmlp_v5(const float* __restrict__ x,  const float* __restrict__ W1,
             const float* __restrict__ b1, const float* __restrict__ W2,
             const float* __restrict__ b2, const float* __restrict__ W3,
             const float* __restrict__ b3, float* __restrict__ out)
{
    __shared__ __bf16 h1h[H1_PL], h1l[H1_PL];
    __shared__ float  parts[64];

    const int t  = threadIdx.x;
    const int g  = t >> 6, l = t & 63;
    const int lr = l & 15, lg = l >> 4;
    const long row0 = (long)blockIdx.x * RR;

    // ---- A-fragments (weights, split bf16) -> registers, once ----
    bf16x8 a1h[2][3], a1l[2][3], a2h[2][4], a2l[2][4];
    #pragma unroll
    for (int t_ = 0; t_ < 2; ++t_) {
        const int n = g * 32 + t_ * 16 + lr;
        #pragma unroll
        for (int ks = 0; ks < 3; ++ks)
            #pragma unroll
            for (int j = 0; j < 8; ++j) {
                float v = W1[(ks * 32 + lg * 8 + j) * U + n];
                __bf16 h, lo; split(v, h, lo);
                a1h[t_][ks][j] = h; a1l[t_][ks][j] = lo;
            }
        #pragma unroll
        for (int ks = 0; ks < 4; ++ks)
            #pragma unroll
            for (int j = 0; j < 8; ++j) {
                float v = W2[(ks * 32 + lg * 8 + j) * U + n];
                __bf16 h, lo; split(v, h, lo);
                a2h[t_][ks][j] = h; a2l[t_][ks][j] = lo;
            }
    }
    // ---- per-lane scalars: n(t_,q) = 32g + 16t_ + 4lg + q matches C-frag rows ----
    float b1v[2][4], w196[2][4], b2v[2][4], w3v[2][4];
    #pragma unroll
    for (int t_ = 0; t_ < 2; ++t_)
        #pragma unroll
        for (int q = 0; q < 4; ++q) {
            int n = g * 32 + t_ * 16 + lg * 4 + q;
            b1v[t_][q]  = b1[n];
            w196[t_][q] = W1[96 * U + n];
            b2v[t_][q]  = b2[n];
            w3v[t_][q]  = W3[n];
        }
    const float b3s = b3[0];

    // ---- buf (recurrent window) -> registers: e = x[row lr, lg*8 .. lg*8+7] ----
    bf16x8 Bbh, Bbl;
    {
        const float* pe = x + (row0 + lr) * XC + lg * 8;    // 8B-aligned
        #pragma unroll
        for (int q = 0; q < 4; ++q) {
            v2f e = *(const v2f*)(pe + 2 * q);
            __bf16 h, lo;
            split(e[0], h, lo); Bbh[2 * q]     = h; Bbl[2 * q]     = lo;
            split(e[1], h, lo); Bbh[2 * q + 1] = h; Bbl[2 * q + 1] = lo;
        }
    }
    const float* xrow  = x + (row0 + lr) * XC;
    const int    h1swz = (lr & 7) << 3;

    for (int i = 0; i < HFWD; ++i) {
        const float fi = (float)i;
        // hoist v global loads (L1-hot sliding window)
        v2f vv[2][4];
        #pragma unroll
        for (int ks = 0; ks < 2; ++ks) {
            const float* p = xrow + 32 + 2 * i + ks * 32 + lg * 8;   // 8B-aligned
            #pragma unroll
            for (int q = 0; q < 4; ++q) vv[ks][q] = *(const v2f*)(p + 2 * q);
        }
        // ================= layer 1 : K=96, 3 independent chains =================
        f32x4 c0[2], c1[2], c2[2];
        #pragma unroll
        for (int t_ = 0; t_ < 2; ++t_)
            #pragma unroll
            for (int q = 0; q < 4; ++q) {
                c0[t_][q] = fmaf(fi, w196[t_][q], b1v[t_][q]);
                c1[t_][q] = 0.0f; c2[t_][q] = 0.0f;
            }
        // kstep 0: buf from registers (no LDS!)
        #pragma unroll
        for (int t_ = 0; t_ < 2; ++t_) {
            c0[t_] = mfma16(a1h[t_][0], Bbh, c0[t_]);
            c1[t_] = mfma16(a1h[t_][0], Bbl, c1[t_]);
            c2[t_] = mfma16(a1l[t_][0], Bbh, c2[t_]);
        }
        // ksteps 1,2: v (split in-register)
        #pragma unroll
        for (int ks = 1; ks <= 2; ++ks) {
            bf16x8 Bh, Bl;
            #pragma unroll
            for (int q = 0; q < 4; ++q) {
                __bf16 h, lo;
                split(vv[ks - 1][q][0], h, lo); Bh[2 * q]     = h; Bl[2 * q]     = lo;
                split(vv[ks - 1][q][1], h, lo); Bh[2 * q + 1] = h; Bl[2 * q + 1] = lo;
            }
            #pragma unroll
            for (int t_ = 0; t_ < 2; ++t_) {
                c0[t_] = mfma16(a1h[t_][ks], Bh, c0[t_]);
                c1[t_] = mfma16(a1h[t_][ks], Bl, c1[t_]);
                c2[t_] = mfma16(a1l[t_][ks], Bh, c2[t_]);
            }
        }
        // epilogue: combine chains + relu + split + store h1
        #pragma unroll
        for (int t_ = 0; t_ < 2; ++t_) {
            bf16x4 hh, ll;
            #pragma unroll
            for (int q = 0; q < 4; ++q) {
                float v = fmaxf(c0[t_][q] + c1[t_][q] + c2[t_][q], 0.0f);
                __bf16 h, lo; split(v, h, lo);
                hh[q] = h; ll[q] = lo;
            }
            int o = (lr * 128 + g * 32 + t_ * 16 + lg * 4) ^ h1swz;
            *(bf16x4*)(h1h + o) = hh;
            *(bf16x4*)(h1l + o) = ll;
        }
        __syncthreads();   // barrier 1: h1 complete

        // ================= layer 2 : K=128, 3 independent chains =================
        f32x4 d0[2], d1[2], d2[2];
        #pragma unroll
        for (int t_ = 0; t_ < 2; ++t_)
            #pragma unroll
            for (int q = 0; q < 4; ++q) {
                d0[t_][q] = b2v[t_][q];
                d1[t_][q] = 0.0f; d2[t_][q] = 0.0f;
            }
        #pragma unroll
        for (int ks = 0; ks < 4; ++ks) {
            int o = (lr * 128 + ks * 32 + lg * 8) ^ h1swz;
            bf16x8 Bh = *(const bf16x8*)(h1h + o);
            bf16x8 Bl = *(const bf16x8*)(h1l + o);
            #pragma unroll
            for (int t_ = 0; t_ < 2; ++t_) {
                d0[t_] = mfma16(a2h[t_][ks], Bh, d0[t_]);
                d1[t_] = mfma16(a2h[t_][ks], Bl, d1[t_]);
                d2[t_] = mfma16(a2l[t_][ks], Bh, d2[t_]);
            }
        }
        // ================= layer 3 =================
        float p = 0.0f;
        #pragma unroll
        for (int t_ = 0; t_ < 2; ++t_)
            #pragma unroll
            for (int q = 0; q < 4; ++q)
                p = fmaf(fmaxf(d0[t_][q] + d1[t_][q] + d2[t_][q], 0.0f), w3v[t_][q], p);
        p += __shfl_xor(p, 16, 64);
        p += __shfl_xor(p, 32, 64);            // sum over this wave's 32 neurons, row lr
        if (l < 16) parts[g * 16 + lr] = p;
        __syncthreads();   // barrier 2: partials ready

        // ---- redundant final reduce (all threads, broadcast reads) ----
        const float s = b3s + parts[lr] + parts[16 + lr] + parts[32 + lr] + parts[48 + lr];
        if (t < 16) out[(row0 + t) * HFWD + i] = s;     // t<16 ⇒ lr==t

        // ---- buf register shift: buf[k] = buf[k+1], buf[31] = s ----
        {
            unsigned int packed = ((unsigned int)bfb(Bbh[0]) << 16) | bfb(Bbl[0]);
            unsigned int up = (unsigned int)__shfl((int)packed, (l + 16) & 63, 64);
            #pragma unroll
            for (int j = 0; j < 7; ++j) { Bbh[j] = Bbh[j + 1]; Bbl[j] = Bbl[j + 1]; }
            if (lg == 3) {
                __bf16 h, lo; split(s, h, lo);
                Bbh[7] = h; Bbl[7] = lo;
            } else {
                Bbh[7] = bbf((unsigned short)(up >> 16));
                Bbl[7] = bbf((unsigned short)(up & 0xffffu));
            }
        }
        // no barrier 3: buf is register-resident; h1 writes of step i+1 are
        // separated from step i's h1 reads by barrier 2.
    }
}

extern "C" void kernel_launch(void* const* d_in, const int* in_sizes, int n_in,
                              void* d_out, int out_size, void* d_ws, size_t ws_size,
                              hipStream_t stream) {
    const float* x  = (const float*)d_in[0];
    const float* W1 = (const float*)d_in[1];
    const float* b1 = (const float*)d_in[2];
    const float* W2 = (const float*)d_in[3];
    const float* b2 = (const float*)d_in[4];
    const float* W3 = (const float*)d_in[5];
    const float* b3 = (const float*)d_in[6];
    float* out = (float*)d_out;

    const int B    = in_sizes[0] / XC;   // 65536
    const int nblk = B / RR;             // 4096

    rmlp_v5<<<nblk, BLOCK, 0, stream>>>(x, W1, b1, W2, b2, W3, b3, out);
}

// Round 11
// 722.237 us; speedup vs baseline: 6.0400x; 1.2944x over previous
//
#include <hip/hip_runtime.h>

typedef float  v2f    __attribute__((ext_vector_type(2)));
typedef float  f32x4  __attribute__((ext_vector_type(4)));
typedef __bf16 bf16x8 __attribute__((ext_vector_type(8)));
typedef __bf16 bf16x4 __attribute__((ext_vector_type(4)));
typedef unsigned int u32x4a4 __attribute__((ext_vector_type(4), aligned(4)));

constexpr int XC = 224, HFWD = 64, U = 128, RR = 16, VW = 192;
#define BLOCK 256
constexpr int H1_PL = RR * 128;

static __device__ __forceinline__ f32x4 mfma16(bf16x8 a, bf16x8 b, f32x4 c) {
    return __builtin_amdgcn_mfma_f32_16x16x32_bf16(a, b, c, 0, 0, 0);
}
static __device__ __forceinline__ void split(float v, __bf16& h, __bf16& l) {
    h = (__bf16)v; l = (__bf16)(v - (float)h);
}
static __device__ __forceinline__ unsigned short bfb(__bf16 b) {
    return __builtin_bit_cast(unsigned short, b);
}
static __device__ __forceinline__ __bf16 bbf(unsigned short u) {
    return __builtin_bit_cast(__bf16, u);
}
static __device__ __forceinline__ bf16x8 ldv(const __bf16* p) {   // 4B-aligned 16B load
    return __builtin_bit_cast(bf16x8, *(const u32x4a4*)p);
}

// ---------------- prepass: split x[:,32:224] into bf16 h/l planes ----------------
extern "C" __global__ __launch_bounds__(256)
void vsplit(const float* __restrict__ x, __bf16* __restrict__ vh,
            __bf16* __restrict__ vl, int B)
{
    int idx = blockIdx.x * 256 + threadIdx.x;
    int row = idx / 24, c8 = (idx - row * 24) * 8;
    if (row >= B) return;
    const float* p = x + (long)row * XC + 32 + c8;
    bf16x8 h, l;
    #pragma unroll
    for (int j = 0; j < 8; ++j) { __bf16 hh, ll; split(p[j], hh, ll); h[j] = hh; l[j] = ll; }
    *(bf16x8*)(vh + (long)row * VW + c8) = h;   // 16B-aligned: 384*row + 16*c8/8
    *(bf16x8*)(vl + (long)row * VW + c8) = l;
}

// ---------------- main kernel ----------------
// 4 waves/block; wave g owns neurons [32g,32g+32) for all 16 rows. lane: lr=l&15
// (batch row / B-col), lg=l>>4 (k-group). A = W^T register-resident (split bf16);
// recurrent buf register-resident. C/D: col=l&15 (row), row=(l>>4)*4+reg (neuron).
template<int PS>
__global__ __launch_bounds__(BLOCK, 2)
void rmlp_v6(const float* __restrict__ x,  const __bf16* __restrict__ vh,
             const __bf16* __restrict__ vl,
             const float* __restrict__ W1, const float* __restrict__ b1,
             const float* __restrict__ W2, const float* __restrict__ b2,
             const float* __restrict__ W3, const float* __restrict__ b3,
             float* __restrict__ out)
{
    __shared__ __bf16 h1h[H1_PL], h1l[H1_PL];
    __shared__ float  parts[64];

    const int t  = threadIdx.x;
    const int g  = t >> 6, l = t & 63;
    const int lr = l & 15, lg = l >> 4;
    const long row0 = (long)blockIdx.x * RR;

    // ---- A-fragments (weights, split bf16) -> registers, once ----
    bf16x8 a1h[2][3], a1l[2][3], a2h[2][4], a2l[2][4];
    #pragma unroll
    for (int t_ = 0; t_ < 2; ++t_) {
        const int n = g * 32 + t_ * 16 + lr;
        #pragma unroll
        for (int ks = 0; ks < 3; ++ks)
            #pragma unroll
            for (int j = 0; j < 8; ++j) {
                float v = W1[(ks * 32 + lg * 8 + j) * U + n];
                __bf16 h, lo; split(v, h, lo);
                a1h[t_][ks][j] = h; a1l[t_][ks][j] = lo;
            }
        #pragma unroll
        for (int ks = 0; ks < 4; ++ks)
            #pragma unroll
            for (int j = 0; j < 8; ++j) {
                float v = W2[(ks * 32 + lg * 8 + j) * U + n];
                __bf16 h, lo; split(v, h, lo);
                a2h[t_][ks][j] = h; a2l[t_][ks][j] = lo;
            }
    }
    // ---- per-lane scalars: n(t_,q) = 32g + 16t_ + 4lg + q matches C-frag rows ----
    float b1v[2][4], w196[2][4], b2v[2][4], w3v[2][4];
    #pragma unroll
    for (int t_ = 0; t_ < 2; ++t_)
        #pragma unroll
        for (int q = 0; q < 4; ++q) {
            int n = g * 32 + t_ * 16 + lg * 4 + q;
            b1v[t_][q]  = b1[n];
            w196[t_][q] = W1[96 * U + n];
            b2v[t_][q]  = b2[n];
            w3v[t_][q]  = W3[n];
        }
    const float b3s = b3[0];

    // ---- buf (recurrent window) -> registers: e = x[row lr, lg*8 .. +7] ----
    bf16x8 Bbh, Bbl;
    {
        const float* pe = x + (row0 + lr) * XC + lg * 8;
        #pragma unroll
        for (int q = 0; q < 4; ++q) {
            v2f e = *(const v2f*)(pe + 2 * q);
            __bf16 h, lo;
            split(e[0], h, lo); Bbh[2 * q]     = h; Bbl[2 * q]     = lo;
            split(e[1], h, lo); Bbh[2 * q + 1] = h; Bbl[2 * q + 1] = lo;
        }
    }
    const float* xrow  = x + (row0 + lr) * XC;
    const __bf16* pvh  = PS ? vh + (row0 + lr) * VW + lg * 8 : nullptr;
    const __bf16* pvl  = PS ? vl + (row0 + lr) * VW + lg * 8 : nullptr;
    const int    h1swz = (lr & 7) << 3;

    // v-fragment loader for step i (ks in {0,1} -> W1 k-tiles 1,2)
    auto LOADF = [&](int i, bf16x8& h0, bf16x8& l0, bf16x8& h1f, bf16x8& l1f) {
        if (PS) {
            h0  = ldv(pvh + 2 * i);        l0  = ldv(pvl + 2 * i);
            h1f = ldv(pvh + 2 * i + 32);   l1f = ldv(pvl + 2 * i + 32);
        } else {
            const float* p0 = xrow + 32 + 2 * i + lg * 8;
            #pragma unroll
            for (int q = 0; q < 4; ++q) {
                v2f d = *(const v2f*)(p0 + 2 * q);
                __bf16 h, lo;
                split(d[0], h, lo); h0[2 * q]     = h; l0[2 * q]     = lo;
                split(d[1], h, lo); h0[2 * q + 1] = h; l0[2 * q + 1] = lo;
            }
            #pragma unroll
            for (int q = 0; q < 4; ++q) {
                v2f d = *(const v2f*)(p0 + 32 + 2 * q);
                __bf16 h, lo;
                split(d[0], h, lo); h1f[2 * q]     = h; l1f[2 * q]     = lo;
                split(d[1], h, lo); h1f[2 * q + 1] = h; l1f[2 * q + 1] = lo;
            }
        }
    };

    bf16x8 cvh0, cvl0, cvh1, cvl1;
    LOADF(0, cvh0, cvl0, cvh1, cvl1);

    for (int i = 0; i < HFWD; ++i) {
        const float fi = (float)i;
        // ========== layer 1: v-chains first (no dependence on buf/w) ==========
        f32x4 c0[2], c1[2], c2[2];
        #pragma unroll
        for (int t_ = 0; t_ < 2; ++t_)
            #pragma unroll
            for (int q = 0; q < 4; ++q) {
                c0[t_][q] = fmaf(fi, w196[t_][q], b1v[t_][q]);
                c1[t_][q] = 0.0f; c2[t_][q] = 0.0f;
            }
        #pragma unroll
        for (int t_ = 0; t_ < 2; ++t_) {
            c0[t_] = mfma16(a1h[t_][1], cvh0, c0[t_]);
            c1[t_] = mfma16(a1h[t_][1], cvl0, c1[t_]);
            c2[t_] = mfma16(a1l[t_][1], cvh0, c2[t_]);
            c0[t_] = mfma16(a1h[t_][2], cvh1, c0[t_]);
            c1[t_] = mfma16(a1h[t_][2], cvl1, c1[t_]);
            c2[t_] = mfma16(a1l[t_][2], cvh1, c2[t_]);
        }
        // prefetch next step's v fragments (in-bounds even at i=63: max idx 191 < 192)
        bf16x8 nvh0, nvl0, nvh1, nvl1;
        LOADF(i + 1, nvh0, nvl0, nvh1, nvl1);

        // kstep 0: buf from registers
        #pragma unroll
        for (int t_ = 0; t_ < 2; ++t_) {
            c0[t_] = mfma16(a1h[t_][0], Bbh, c0[t_]);
            c1[t_] = mfma16(a1h[t_][0], Bbl, c1[t_]);
            c2[t_] = mfma16(a1l[t_][0], Bbh, c2[t_]);
        }
        // epilogue: combine chains + relu + split + store h1
        #pragma unroll
        for (int t_ = 0; t_ < 2; ++t_) {
            bf16x4 hh, ll;
            #pragma unroll
            for (int q = 0; q < 4; ++q) {
                float v = fmaxf(c0[t_][q] + c1[t_][q] + c2[t_][q], 0.0f);
                __bf16 h, lo; split(v, h, lo);
                hh[q] = h; ll[q] = lo;
            }
            int o = (lr * 128 + g * 32 + t_ * 16 + lg * 4) ^ h1swz;
            *(bf16x4*)(h1h + o) = hh;
            *(bf16x4*)(h1l + o) = ll;
        }
        __syncthreads();   // barrier 1: h1 complete

        // ========== layer 2: K=128, 3 independent chains ==========
        f32x4 d0[2], d1[2], d2[2];
        #pragma unroll
        for (int t_ = 0; t_ < 2; ++t_)
            #pragma unroll
            for (int q = 0; q < 4; ++q) {
                d0[t_][q] = b2v[t_][q];
                d1[t_][q] = 0.0f; d2[t_][q] = 0.0f;
            }
        #pragma unroll
        for (int ks = 0; ks < 4; ++ks) {
            int o = (lr * 128 + ks * 32 + lg * 8) ^ h1swz;
            bf16x8 Bh = *(const bf16x8*)(h1h + o);
            bf16x8 Bl = *(const bf16x8*)(h1l + o);
            #pragma unroll
            for (int t_ = 0; t_ < 2; ++t_) {
                d0[t_] = mfma16(a2h[t_][ks], Bh, d0[t_]);
                d1[t_] = mfma16(a2h[t_][ks], Bl, d1[t_]);
                d2[t_] = mfma16(a2l[t_][ks], Bh, d2[t_]);
            }
        }
        // ========== layer 3 ==========
        float p = 0.0f;
        #pragma unroll
        for (int t_ = 0; t_ < 2; ++t_)
            #pragma unroll
            for (int q = 0; q < 4; ++q)
                p = fmaf(fmaxf(d0[t_][q] + d1[t_][q] + d2[t_][q], 0.0f), w3v[t_][q], p);
        p += __shfl_xor(p, 16, 64);
        p += __shfl_xor(p, 32, 64);
        if (l < 16) parts[g * 16 + lr] = p;
        __syncthreads();   // barrier 2: partials ready

        const float s = b3s + parts[lr] + parts[16 + lr] + parts[32 + lr] + parts[48 + lr];
        if (t < 16) out[(row0 + t) * HFWD + i] = s;

        // buf register shift: buf[k] = buf[k+1], buf[31] = s
        {
            unsigned int packed = ((unsigned int)bfb(Bbh[0]) << 16) | bfb(Bbl[0]);
            unsigned int up = (unsigned int)__shfl((int)packed, (l + 16) & 63, 64);
            #pragma unroll
            for (int j = 0; j < 7; ++j) { Bbh[j] = Bbh[j + 1]; Bbl[j] = Bbl[j + 1]; }
            if (lg == 3) {
                __bf16 h, lo; split(s, h, lo);
                Bbh[7] = h; Bbl[7] = lo;
            } else {
                Bbh[7] = bbf((unsigned short)(up >> 16));
                Bbl[7] = bbf((unsigned short)(up & 0xffffu));
            }
        }
        // rotate pipeline regs (static, SSA-friendly)
        cvh0 = nvh0; cvl0 = nvl0; cvh1 = nvh1; cvl1 = nvl1;
    }
}

extern "C" void kernel_launch(void* const* d_in, const int* in_sizes, int n_in,
                              void* d_out, int out_size, void* d_ws, size_t ws_size,
                              hipStream_t stream) {
    const float* x  = (const float*)d_in[0];
    const float* W1 = (const float*)d_in[1];
    const float* b1 = (const float*)d_in[2];
    const float* W2 = (const float*)d_in[3];
    const float* b2 = (const float*)d_in[4];
    const float* W3 = (const float*)d_in[5];
    const float* b3 = (const float*)d_in[6];
    float* out = (float*)d_out;

    const int B    = in_sizes[0] / XC;   // 65536
    const int nblk = B / RR;             // 4096
    const size_t plane = (size_t)B * VW * sizeof(__bf16);   // 25.2 MB
    const size_t need  = 2 * plane;                         // 50.3 MB

    if (ws_size >= need) {
        __bf16* vh = (__bf16*)d_ws;
        __bf16* vl = vh + (size_t)B * VW;
        vsplit<<<(B * 24 + 255) / 256, 256, 0, stream>>>(x, vh, vl, B);
        rmlp_v6<1><<<nblk, BLOCK, 0, stream>>>(x, vh, vl, W1, b1, W2, b2, W3, b3, out);
    } else {
        rmlp_v6<0><<<nblk, BLOCK, 0, stream>>>(x, nullptr, nullptr, W1, b1, W2, b2, W3, b3, out);
    }
}